// Round 1
// baseline (304.084 us; speedup 1.0000x reference)
//
#include <hip/hip_runtime.h>
#include <stdint.h>

// IDXST(4096x4096): y[r][k] = sum_n x[r][n] * sin(pi*n*(2k+1)/(2N)), N=4096.
// Cast as bf16 MFMA GEMM: Y = Xb * Bt^T with Bt[c][n] = sin(pi*n*(2c+1)/8192).
// Workspace: [0,32MB) Xb bf16, [32MB,64MB) Bt bf16.

#define NN 4096
#define TM 128
#define TN 128
#define TK 64

typedef __attribute__((ext_vector_type(8))) short short8;   // 8 x bf16 (4 VGPRs)
typedef __attribute__((ext_vector_type(4))) float f32x4;    // MFMA acc

// fp32 -> bf16 round-to-nearest-even (inputs are finite; no NaN handling needed)
__device__ __forceinline__ unsigned short f2bf(float f) {
  unsigned int u = __float_as_uint(f);
  u += 0x7fffu + ((u >> 16) & 1u);
  return (unsigned short)(u >> 16);
}

// async global->LDS, 16B per lane. LDS dest is wave-uniform base + lane*16
// (m104/m108), so pass the wave-uniform base; per-lane global src.
__device__ __forceinline__ void async_load16(const void* g, void* lds) {
  __builtin_amdgcn_global_load_lds(
      (const __attribute__((address_space(1))) unsigned int*)g,
      (__attribute__((address_space(3))) unsigned int*)lds, 16, 0, 0);
}

__global__ void convert_x_kernel(const float* __restrict__ x,
                                 unsigned short* __restrict__ xb) {
  int i = blockIdx.x * blockDim.x + threadIdx.x;  // over NN*NN/4
  float4 v = ((const float4*)x)[i];
  ushort4 o;
  o.x = f2bf(v.x); o.y = f2bf(v.y); o.z = f2bf(v.z); o.w = f2bf(v.w);
  ((ushort4*)xb)[i] = o;
}

__global__ void gen_bt_kernel(unsigned short* __restrict__ Bt) {
  // Bt[c][n] = sin(pi * n * (2c+1) / 8192); phase integer mod 16384 is exact.
  int i = blockIdx.x * blockDim.x + threadIdx.x;  // over NN*NN/4
  int n0 = (i & 1023) << 2;                       // n base (k-dim), 0..4092
  int c = i >> 10;                                // output index, 0..4095
  unsigned int tw = 2u * (unsigned)c + 1u;
  const float sc = 3.14159265358979323846f / 8192.0f;
  ushort4 o;
  unsigned int p;
  p = ((unsigned)(n0 + 0) * tw) & 16383u; o.x = f2bf(__sinf((float)p * sc));
  p = ((unsigned)(n0 + 1) * tw) & 16383u; o.y = f2bf(__sinf((float)p * sc));
  p = ((unsigned)(n0 + 2) * tw) & 16383u; o.z = f2bf(__sinf((float)p * sc));
  p = ((unsigned)(n0 + 3) * tw) & 16383u; o.w = f2bf(__sinf((float)p * sc));
  ((ushort4*)Bt)[i] = o;
}

// m97-structure GEMM: C[M][N] = A[M][K] * B[N][K]^T, both operands bf16
// row-major with K contiguous. 128x128 C-tile / block, 256 thr (4 waves, 2x2),
// each wave 4x4 grid of 16x16x32 MFMA, BK=64, 32 KiB LDS, width-16
// global_load_lds staging.
__global__ __launch_bounds__(256) void gemm_bt_kernel(
    const unsigned short* __restrict__ A,   // [NN][NN] bf16
    const unsigned short* __restrict__ B,   // [NN][NN] bf16 (Bt: row=c, col=n)
    float* __restrict__ C) {
  __shared__ __align__(16) unsigned short lA[TM * TK];  // 16 KiB
  __shared__ __align__(16) unsigned short lB[TN * TK];  // 16 KiB

  const int tid = threadIdx.x;
  const int wave = tid >> 6;
  const int lane = tid & 63;
  const int quad = lane >> 4;   // 0..3
  const int lr = lane & 15;     // 0..15
  const int wr = wave >> 1;     // wave row in 2x2
  const int wc = wave & 1;      // wave col in 2x2

  const int row0 = blockIdx.y * TM;
  const int col0 = blockIdx.x * TN;

  // staging geometry: per round, 256 thr x 16 B = 4 KiB = 32 rows of 128 B.
  const int srow = wave * 8 + (lane >> 3);  // row within 32-row round
  const int scol = (lane & 7) * 8;          // element col (8 bf16 = 16 B)

  f32x4 acc[4][4];
#pragma unroll
  for (int i = 0; i < 4; ++i)
#pragma unroll
    for (int j = 0; j < 4; ++j)
      acc[i][j] = (f32x4){0.f, 0.f, 0.f, 0.f};

  for (int k0 = 0; k0 < NN; k0 += TK) {
    __syncthreads();  // prev compute done before overwriting LDS
#pragma unroll
    for (int r = 0; r < 4; ++r) {
      const int rr = r * 32 + srow;
      // wave-uniform LDS base: start of this wave's 1 KiB slice in round r
      async_load16(&A[(size_t)(row0 + rr) * NN + k0 + scol],
                   &lA[(r * 32 + wave * 8) * TK]);
      async_load16(&B[(size_t)(col0 + rr) * NN + k0 + scol],
                   &lB[(r * 32 + wave * 8) * TK]);
    }
    __syncthreads();  // compiler emits s_waitcnt vmcnt(0) before barrier

#pragma unroll
    for (int kk = 0; kk < TK; kk += 32) {
      short8 af[4], bfv[4];
#pragma unroll
      for (int i = 0; i < 4; ++i) {
        // A-frag: A[m=lr][k=quad*8+j]; B-frag mirrors with n=lr.
        af[i]  = *(const short8*)&lA[(wr * 64 + i * 16 + lr) * TK + kk + quad * 8];
        bfv[i] = *(const short8*)&lB[(wc * 64 + i * 16 + lr) * TK + kk + quad * 8];
      }
#pragma unroll
      for (int i = 0; i < 4; ++i)
#pragma unroll
        for (int j = 0; j < 4; ++j)
          acc[i][j] = __builtin_amdgcn_mfma_f32_16x16x32_bf16(
              af[i], bfv[j], acc[i][j], 0, 0, 0);
    }
  }

  // epilogue: C/D layout col=lane&15, row=quad*4+reg (m89/m91-verified)
#pragma unroll
  for (int i = 0; i < 4; ++i)
#pragma unroll
    for (int j = 0; j < 4; ++j)
#pragma unroll
      for (int r = 0; r < 4; ++r) {
        int row = row0 + wr * 64 + i * 16 + quad * 4 + r;
        int col = col0 + wc * 64 + j * 16 + lr;
        C[(size_t)row * NN + col] = acc[i][j][r];
      }
}

extern "C" void kernel_launch(void* const* d_in, const int* in_sizes, int n_in,
                              void* d_out, int out_size, void* d_ws, size_t ws_size,
                              hipStream_t stream) {
  const float* x = (const float*)d_in[0];
  float* out = (float*)d_out;
  unsigned short* xb = (unsigned short*)d_ws;                 // 32 MiB
  unsigned short* Bt = xb + (size_t)NN * NN;                  // 32 MiB

  const int nvec = NN * NN / 4;  // 4 elements / thread
  convert_x_kernel<<<nvec / 256, 256, 0, stream>>>(x, xb);
  gen_bt_kernel<<<nvec / 256, 256, 0, stream>>>(Bt);

  dim3 grid(NN / TN, NN / TM);
  gemm_bt_kernel<<<grid, 256, 0, stream>>>(xb, Bt, out);
}

// Round 2
// 264.131 us; speedup vs baseline: 1.1513x; 1.1513x over previous
//
#include <hip/hip_runtime.h>
#include <stdint.h>

// IDXST(4096x4096): y[r][k] = sum_n x[r][n] * sin(pi*n*(2k+1)/(2N)), N=4096.
// Cast as bf16 MFMA GEMM: Y = Xb * Bt^T with Bt[c][n] = sin(pi*n*(2c+1)/8192).
// Workspace: [0,32MB) Xb bf16, [32MB,64MB) Bt bf16.
//
// R2 change: XOR-swizzled LDS layout (LDS[row][blk] = global chunk
// blk^(row&7)) to kill the 16-way ds_read_b128 bank conflicts measured in R1
// (SQ_LDS_BANK_CONFLICT=5e7 ~= 38% of kernel cycles). Swizzle is applied on
// the global-source side of global_load_lds (LDS dest is forced to
// wave-uniform base + lane*16).

#define NN 4096
#define TM 128
#define TN 128
#define TK 64

typedef __attribute__((ext_vector_type(8))) short short8;   // 8 x bf16 (4 VGPRs)
typedef __attribute__((ext_vector_type(4))) float f32x4;    // MFMA acc

// fp32 -> bf16 round-to-nearest-even (inputs finite)
__device__ __forceinline__ unsigned short f2bf(float f) {
  unsigned int u = __float_as_uint(f);
  u += 0x7fffu + ((u >> 16) & 1u);
  return (unsigned short)(u >> 16);
}

__device__ __forceinline__ void async_load16(const void* g, void* lds) {
  __builtin_amdgcn_global_load_lds(
      (const __attribute__((address_space(1))) unsigned int*)g,
      (__attribute__((address_space(3))) unsigned int*)lds, 16, 0, 0);
}

#define NVEC (NN * NN / 4)

// Fused prep: blocks [0, NVEC/256) convert x -> bf16; blocks [NVEC/256, 2*..)
// generate Bt. One dispatch instead of two.
__global__ void prep_kernel(const float* __restrict__ x,
                            unsigned short* __restrict__ xb,
                            unsigned short* __restrict__ Bt) {
  int gi = blockIdx.x * blockDim.x + threadIdx.x;
  if (gi < NVEC) {
    float4 v = ((const float4*)x)[gi];
    ushort4 o;
    o.x = f2bf(v.x); o.y = f2bf(v.y); o.z = f2bf(v.z); o.w = f2bf(v.w);
    ((ushort4*)xb)[gi] = o;
  } else {
    int i = gi - NVEC;
    int n0 = (i & 1023) << 2;                     // n (K dim), 0..4092
    int c = i >> 10;                              // output col, 0..4095
    unsigned int tw = 2u * (unsigned)c + 1u;
    const float sc = 3.14159265358979323846f / 8192.0f;
    ushort4 o;
    unsigned int p;
    p = ((unsigned)(n0 + 0) * tw) & 16383u; o.x = f2bf(__sinf((float)p * sc));
    p = ((unsigned)(n0 + 1) * tw) & 16383u; o.y = f2bf(__sinf((float)p * sc));
    p = ((unsigned)(n0 + 2) * tw) & 16383u; o.z = f2bf(__sinf((float)p * sc));
    p = ((unsigned)(n0 + 3) * tw) & 16383u; o.w = f2bf(__sinf((float)p * sc));
    ((ushort4*)Bt)[i] = o;
  }
}

// C[M][N] = A[M][K] * B[N][K]^T, bf16, K contiguous. 128x128 tile / block,
// 4 waves (2x2), 4x4 grid of 16x16x32 MFMA per wave, BK=64, 32 KiB LDS,
// width-16 global_load_lds staging, XOR-swizzled LDS blocks.
__global__ __launch_bounds__(256) void gemm_bt_kernel(
    const unsigned short* __restrict__ A,
    const unsigned short* __restrict__ B,
    float* __restrict__ C) {
  __shared__ __align__(16) unsigned short lA[TM * TK];  // 16 KiB
  __shared__ __align__(16) unsigned short lB[TN * TK];  // 16 KiB

  const int tid = threadIdx.x;
  const int wave = tid >> 6;
  const int lane = tid & 63;
  const int quad = lane >> 4;   // 0..3
  const int lr = lane & 15;     // 0..15
  const int wr = wave >> 1;
  const int wc = wave & 1;

  const int row0 = blockIdx.y * TM;
  const int col0 = blockIdx.x * TN;

  // staging: per round, 256 thr x 16 B = 32 rows of 128 B. lane l of a wave
  // lands at LDS slot (row = l>>3, blk = l&7) within the wave's 8-row slice;
  // fetch global chunk (l&7)^(l>>3) so LDS[row][blk] = global[row][blk^(row&7)].
  const int srow = wave * 8 + (lane >> 3);
  const int scol = ((lane & 7) ^ (lane >> 3)) * 8;   // swizzled global chunk

  f32x4 acc[4][4];
#pragma unroll
  for (int i = 0; i < 4; ++i)
#pragma unroll
    for (int j = 0; j < 4; ++j)
      acc[i][j] = (f32x4){0.f, 0.f, 0.f, 0.f};

  for (int k0 = 0; k0 < NN; k0 += TK) {
    __syncthreads();
#pragma unroll
    for (int r = 0; r < 4; ++r) {
      const int rr = r * 32 + srow;
      async_load16(&A[(size_t)(row0 + rr) * NN + k0 + scol],
                   &lA[(r * 32 + wave * 8) * TK]);
      async_load16(&B[(size_t)(col0 + rr) * NN + k0 + scol],
                   &lB[(r * 32 + wave * 8) * TK]);
    }
    __syncthreads();

#pragma unroll
    for (int kk = 0; kk < TK; kk += 32) {
      short8 af[4], bfv[4];
#pragma unroll
      for (int i = 0; i < 4; ++i) {
        // un-swizzle: global blk (kk>>3)+quad lives at LDS blk ^(row&7), row&7==lr&7
        const int sa = (((kk >> 3) + quad) ^ (lr & 7)) * 8;
        af[i]  = *(const short8*)&lA[(wr * 64 + i * 16 + lr) * TK + sa];
        bfv[i] = *(const short8*)&lB[(wc * 64 + i * 16 + lr) * TK + sa];
      }
#pragma unroll
      for (int i = 0; i < 4; ++i)
#pragma unroll
        for (int j = 0; j < 4; ++j)
          acc[i][j] = __builtin_amdgcn_mfma_f32_16x16x32_bf16(
              af[i], bfv[j], acc[i][j], 0, 0, 0);
    }
  }

  // epilogue: C/D layout col=lane&15, row=quad*4+reg (m89/m91-verified)
#pragma unroll
  for (int i = 0; i < 4; ++i)
#pragma unroll
    for (int j = 0; j < 4; ++j)
#pragma unroll
      for (int r = 0; r < 4; ++r) {
        int row = row0 + wr * 64 + i * 16 + quad * 4 + r;
        int col = col0 + wc * 64 + j * 16 + lr;
        C[(size_t)row * NN + col] = acc[i][j][r];
      }
}

extern "C" void kernel_launch(void* const* d_in, const int* in_sizes, int n_in,
                              void* d_out, int out_size, void* d_ws, size_t ws_size,
                              hipStream_t stream) {
  const float* x = (const float*)d_in[0];
  float* out = (float*)d_out;
  unsigned short* xb = (unsigned short*)d_ws;                 // 32 MiB
  unsigned short* Bt = xb + (size_t)NN * NN;                  // 32 MiB

  prep_kernel<<<2 * NVEC / 256, 256, 0, stream>>>(x, xb, Bt);

  dim3 grid(NN / TN, NN / TM);
  gemm_bt_kernel<<<grid, 256, 0, stream>>>(xb, Bt, out);
}

// Round 3
// 250.907 us; speedup vs baseline: 1.2119x; 1.0527x over previous
//
#include <hip/hip_runtime.h>
#include <stdint.h>

// IDXST(4096x4096): y[r][k] = sum_n x[r][n] * sin(pi*n*(2k+1)/(2N)), N=4096.
// R3: mirror-fold. S[n][N-1-k] = (-1)^(n+1) S[n][k], so with
//   v[k] = sum_{n even} x[n] S[n][k],  u[k] = sum_{n odd} x[n] S[n][k]
// for k in [0,2048):  y[k] = v+u,  y[4095-k] = u-v.  Half the MFMA FLOPs.
// Data is packed in 32-even|32-odd blocks so each 128-B staged LDS row is
// [even 64B | odd 64B] -- staging/swizzle geometry identical to the R2 kernel
// (which measured 0 bank conflicts); kk=0 accumulates v, kk=32 accumulates u.
// Workspace: [0,32MB) xd (packed x, bf16), [32MB,48MB) Bd (2048x4096 bf16).

#define NN 4096
#define TM 128
#define TN 128
#define TK 64

typedef __attribute__((ext_vector_type(8))) short short8;
typedef __attribute__((ext_vector_type(4))) float f32x4;

__device__ __forceinline__ unsigned short f2bf(float f) {
  unsigned int u = __float_as_uint(f);
  u += 0x7fffu + ((u >> 16) & 1u);
  return (unsigned short)(u >> 16);
}

__device__ __forceinline__ void async_load16(const void* g, void* lds) {
  __builtin_amdgcn_global_load_lds(
      (const __attribute__((address_space(1))) unsigned int*)g,
      (__attribute__((address_space(3))) unsigned int*)lds, 16, 0, 0);
}

#define NP8 (NN * NN / 8)          // xd threads: 8 floats each
#define NBD (2048 * NN / 4)        // Bd threads: 4 entries each

// Fused prep.
// xd[r][b*64 + j]      = x[r][2*(b*32+j)]     (even)   j<32
// xd[r][b*64 + 32 + j] = x[r][2*(b*32+j)+1]   (odd)
// Bd[k][b*64 + j]      = sin(pi*(2*(b*32+j)  )*(2k+1)/8192)
// Bd[k][b*64 + 32 + j] = sin(pi*(2*(b*32+j)+1)*(2k+1)/8192)
__global__ void prep_kernel(const float* __restrict__ x,
                            unsigned short* __restrict__ xd,
                            unsigned short* __restrict__ Bd) {
  int gi = blockIdx.x * blockDim.x + threadIdx.x;
  if (gi < NP8) {
    int g = gi & 511;              // group of 8 floats within row
    int r = gi >> 9;
    const float4* src = (const float4*)(x + (size_t)r * NN + g * 8);
    float4 v0 = src[0], v1 = src[1];
    int b = g >> 3;
    int j = (g & 7) * 4;
    ushort4 ev, od;
    ev.x = f2bf(v0.x); ev.y = f2bf(v0.z); ev.z = f2bf(v1.x); ev.w = f2bf(v1.z);
    od.x = f2bf(v0.y); od.y = f2bf(v0.w); od.z = f2bf(v1.y); od.w = f2bf(v1.w);
    *(ushort4*)&xd[(size_t)r * NN + b * 64 + j] = ev;
    *(ushort4*)&xd[(size_t)r * NN + b * 64 + 32 + j] = od;
  } else {
    int i = gi - NP8;
    int p = (i & 1023) * 4;        // position within packed row
    int k = i >> 10;               // 0..2047
    unsigned int tw = 2u * (unsigned)k + 1u;
    int b = p >> 6, off = p & 63;
    int odd = (off >= 32) ? 1 : 0;
    int mbase = b * 32 + (off & 31);
    const float sc = 3.14159265358979323846f / 8192.0f;
    ushort4 o;
    unsigned int ph;
    ph = ((unsigned)(2 * (mbase + 0) + odd) * tw) & 16383u; o.x = f2bf(__sinf((float)ph * sc));
    ph = ((unsigned)(2 * (mbase + 1) + odd) * tw) & 16383u; o.y = f2bf(__sinf((float)ph * sc));
    ph = ((unsigned)(2 * (mbase + 2) + odd) * tw) & 16383u; o.z = f2bf(__sinf((float)ph * sc));
    ph = ((unsigned)(2 * (mbase + 3) + odd) * tw) & 16383u; o.w = f2bf(__sinf((float)ph * sc));
    *(ushort4*)&Bd[(size_t)k * NN + p] = o;
  }
}

// Folded GEMM: grid (2048/TN, 4096/TM). Per block: 128 rows x 128 k-cols,
// writes 256 output cols (k and its mirror 4095-k).
__global__ __launch_bounds__(256) void gemm_fold_kernel(
    const unsigned short* __restrict__ A,   // xd [4096][4096]
    const unsigned short* __restrict__ B,   // Bd [2048][4096]
    float* __restrict__ C) {
  __shared__ __align__(16) unsigned short lA[TM * TK];
  __shared__ __align__(16) unsigned short lB[TN * TK];

  const int tid = threadIdx.x;
  const int wave = tid >> 6;
  const int lane = tid & 63;
  const int quad = lane >> 4;
  const int lr = lane & 15;
  const int wr = wave >> 1;
  const int wc = wave & 1;

  const int row0 = blockIdx.y * TM;
  const int col0 = blockIdx.x * TN;        // k-col base, 0..1920

  const int srow = wave * 8 + (lane >> 3);
  const int scol = ((lane & 7) ^ (lane >> 3)) * 8;   // XOR-swizzled chunk

  f32x4 accV[4][4], accU[4][4];
#pragma unroll
  for (int i = 0; i < 4; ++i)
#pragma unroll
    for (int j = 0; j < 4; ++j) {
      accV[i][j] = (f32x4){0.f, 0.f, 0.f, 0.f};
      accU[i][j] = (f32x4){0.f, 0.f, 0.f, 0.f};
    }

  for (int k0 = 0; k0 < NN; k0 += TK) {    // packed width = 4096
    __syncthreads();
#pragma unroll
    for (int r = 0; r < 4; ++r) {
      const int rr = r * 32 + srow;
      async_load16(&A[(size_t)(row0 + rr) * NN + k0 + scol],
                   &lA[(r * 32 + wave * 8) * TK]);
      async_load16(&B[(size_t)(col0 + rr) * NN + k0 + scol],
                   &lB[(r * 32 + wave * 8) * TK]);
    }
    __syncthreads();

#pragma unroll
    for (int kk = 0; kk < TK; kk += 32) {  // kk=0: even half -> V; kk=32: odd -> U
      short8 af[4], bfv[4];
#pragma unroll
      for (int i = 0; i < 4; ++i) {
        const int sa = (((kk >> 3) + quad) ^ (lr & 7)) * 8;
        af[i]  = *(const short8*)&lA[(wr * 64 + i * 16 + lr) * TK + sa];
        bfv[i] = *(const short8*)&lB[(wc * 64 + i * 16 + lr) * TK + sa];
      }
#pragma unroll
      for (int i = 0; i < 4; ++i)
#pragma unroll
        for (int j = 0; j < 4; ++j) {
          if (kk == 0)
            accV[i][j] = __builtin_amdgcn_mfma_f32_16x16x32_bf16(
                af[i], bfv[j], accV[i][j], 0, 0, 0);
          else
            accU[i][j] = __builtin_amdgcn_mfma_f32_16x16x32_bf16(
                af[i], bfv[j], accU[i][j], 0, 0, 0);
        }
    }
  }

  // epilogue: y[k] = v+u, y[4095-k] = u-v   (C/D layout: col=lr, row=quad*4+r)
#pragma unroll
  for (int i = 0; i < 4; ++i)
#pragma unroll
    for (int j = 0; j < 4; ++j)
#pragma unroll
      for (int r = 0; r < 4; ++r) {
        int row = row0 + wr * 64 + i * 16 + quad * 4 + r;
        int cl = wc * 64 + j * 16 + lr;
        float v = accV[i][j][r], u = accU[i][j][r];
        C[(size_t)row * NN + col0 + cl] = v + u;
        C[(size_t)row * NN + (NN - 1 - col0 - cl)] = u - v;
      }
}

extern "C" void kernel_launch(void* const* d_in, const int* in_sizes, int n_in,
                              void* d_out, int out_size, void* d_ws, size_t ws_size,
                              hipStream_t stream) {
  const float* x = (const float*)d_in[0];
  float* out = (float*)d_out;
  unsigned short* xd = (unsigned short*)d_ws;                 // 32 MiB
  unsigned short* Bd = xd + (size_t)NN * NN;                  // 16 MiB

  prep_kernel<<<(NP8 + NBD) / 256, 256, 0, stream>>>(x, xd, Bd);

  dim3 grid(2048 / TN, NN / TM);
  gemm_fold_kernel<<<grid, 256, 0, stream>>>(xd, Bd, out);
}

// Round 4
// 211.987 us; speedup vs baseline: 1.4344x; 1.1836x over previous
//
#include <hip/hip_runtime.h>
#include <stdint.h>

// IDXST(4096x4096): y[r][k] = sum_n x[r][n] * sin(pi*n*(2k+1)/(2N)), N=4096.
// R4: mirror-fold as TWO independent GEMMs to restore R2's proven block shape:
//   V = Xe * Se^T, U = Xo * So^T   (M=4096, N=2048, K=2048 each)
//   y[k] = v+u,  y[4095-k] = u-v   for k in [0,2048)
// One GEMM dispatch, grid (16,32,2) = 1024 blocks (z selects V/U), single 4x4
// acc per wave (VGPR ~92, 4+ blocks/CU resident -- fixes R3's 2-blocks/CU,
// MfmaUtil 17.5% collapse). V,U staged into d_out halves; an in-place combine
// pass (closed quad-pairs {k, 2044-k}, no cross-thread hazard) finishes.
// Workspace (48 MB): xe,xo [4096][2048] bf16; Be,Bo [2048][2048] bf16.

#define NN 4096
#define NH 2048
#define TM 128
#define TN 128
#define TK 64

typedef __attribute__((ext_vector_type(8))) short short8;
typedef __attribute__((ext_vector_type(4))) float f32x4;

__device__ __forceinline__ unsigned short f2bf(float f) {
  unsigned int u = __float_as_uint(f);
  u += 0x7fffu + ((u >> 16) & 1u);
  return (unsigned short)(u >> 16);
}

__device__ __forceinline__ void async_load16(const void* g, void* lds) {
  __builtin_amdgcn_global_load_lds(
      (const __attribute__((address_space(1))) unsigned int*)g,
      (__attribute__((address_space(3))) unsigned int*)lds, 16, 0, 0);
}

#define NP8 (NN * NN / 8)       // 2M threads: x -> xe|xo (8 floats each)
#define NB4 (NH * NH / 4)       // 1M threads per B matrix

// Fused prep: xe[r][m]=x[r][2m], xo[r][m]=x[r][2m+1];
// Be[k][m]=sin(pi*2m*(2k+1)/8192), Bo[k][m]=sin(pi*(2m+1)*(2k+1)/8192).
__global__ void prep_kernel(const float* __restrict__ x,
                            unsigned short* __restrict__ xe,
                            unsigned short* __restrict__ xo,
                            unsigned short* __restrict__ Be,
                            unsigned short* __restrict__ Bo) {
  int gi = blockIdx.x * blockDim.x + threadIdx.x;
  if (gi < NP8) {
    int g = gi & 511;            // group of 8 floats within row
    int r = gi >> 9;
    const float4* src = (const float4*)(x + (size_t)r * NN + g * 8);
    float4 v0 = src[0], v1 = src[1];
    ushort4 ev, od;
    ev.x = f2bf(v0.x); ev.y = f2bf(v0.z); ev.z = f2bf(v1.x); ev.w = f2bf(v1.z);
    od.x = f2bf(v0.y); od.y = f2bf(v0.w); od.z = f2bf(v1.y); od.w = f2bf(v1.w);
    *(ushort4*)&xe[(size_t)r * NH + g * 4] = ev;
    *(ushort4*)&xo[(size_t)r * NH + g * 4] = od;
  } else {
    int i = gi - NP8;
    int odd = 0;
    if (i >= NB4) { i -= NB4; odd = 1; }
    int m0 = (i & 511) * 4;      // m base
    int k = i >> 9;              // 0..2047
    unsigned int tw = 2u * (unsigned)k + 1u;
    const float sc = 3.14159265358979323846f / 8192.0f;
    ushort4 o;
    unsigned int ph;
    ph = ((unsigned)(2 * (m0 + 0) + odd) * tw) & 16383u; o.x = f2bf(__sinf((float)ph * sc));
    ph = ((unsigned)(2 * (m0 + 1) + odd) * tw) & 16383u; o.y = f2bf(__sinf((float)ph * sc));
    ph = ((unsigned)(2 * (m0 + 2) + odd) * tw) & 16383u; o.z = f2bf(__sinf((float)ph * sc));
    ph = ((unsigned)(2 * (m0 + 3) + odd) * tw) & 16383u; o.w = f2bf(__sinf((float)ph * sc));
    unsigned short* B = odd ? Bo : Be;
    *(ushort4*)&B[(size_t)k * NH + m0] = o;
  }
}

// R2-structure GEMM, K=2048, z in {0,1} selects (xe,Be)->out[:,0:2048) or
// (xo,Bo)->out[:,2048:4096). 128x128 tile, 4 waves 2x2, 4x4 16x16x32 MFMA,
// BK=64, 32 KiB LDS, width-16 global_load_lds, XOR-swizzled (0 conflicts).
__global__ __launch_bounds__(256) void gemm_vu_kernel(
    const unsigned short* __restrict__ xeo,   // xe | xo, each [NN][NH]
    const unsigned short* __restrict__ Beo,   // Be | Bo, each [NH][NH]
    float* __restrict__ out) {
  __shared__ __align__(16) unsigned short lA[TM * TK];
  __shared__ __align__(16) unsigned short lB[TN * TK];

  const int z = blockIdx.z;
  const unsigned short* A = xeo + (size_t)z * NN * NH;
  const unsigned short* B = Beo + (size_t)z * NH * NH;
  float* O = out + (size_t)z * NH;   // V -> cols [0,2048), U -> [2048,4096)

  const int tid = threadIdx.x;
  const int wave = tid >> 6;
  const int lane = tid & 63;
  const int quad = lane >> 4;
  const int lr = lane & 15;
  const int wr = wave >> 1;
  const int wc = wave & 1;

  const int row0 = blockIdx.y * TM;
  const int col0 = blockIdx.x * TN;

  const int srow = wave * 8 + (lane >> 3);
  const int scol = ((lane & 7) ^ (lane >> 3)) * 8;   // XOR-swizzled chunk

  f32x4 acc[4][4];
#pragma unroll
  for (int i = 0; i < 4; ++i)
#pragma unroll
    for (int j = 0; j < 4; ++j)
      acc[i][j] = (f32x4){0.f, 0.f, 0.f, 0.f};

  for (int k0 = 0; k0 < NH; k0 += TK) {
    __syncthreads();
#pragma unroll
    for (int r = 0; r < 4; ++r) {
      const int rr = r * 32 + srow;
      async_load16(&A[(size_t)(row0 + rr) * NH + k0 + scol],
                   &lA[(r * 32 + wave * 8) * TK]);
      async_load16(&B[(size_t)(col0 + rr) * NH + k0 + scol],
                   &lB[(r * 32 + wave * 8) * TK]);
    }
    __syncthreads();

#pragma unroll
    for (int kk = 0; kk < TK; kk += 32) {
      short8 af[4], bfv[4];
#pragma unroll
      for (int i = 0; i < 4; ++i) {
        const int sa = (((kk >> 3) + quad) ^ (lr & 7)) * 8;
        af[i]  = *(const short8*)&lA[(wr * 64 + i * 16 + lr) * TK + sa];
        bfv[i] = *(const short8*)&lB[(wc * 64 + i * 16 + lr) * TK + sa];
      }
#pragma unroll
      for (int i = 0; i < 4; ++i)
#pragma unroll
        for (int j = 0; j < 4; ++j)
          acc[i][j] = __builtin_amdgcn_mfma_f32_16x16x32_bf16(
              af[i], bfv[j], acc[i][j], 0, 0, 0);
    }
  }

  // C/D layout: col=lane&15, row=quad*4+reg
#pragma unroll
  for (int i = 0; i < 4; ++i)
#pragma unroll
    for (int j = 0; j < 4; ++j)
#pragma unroll
      for (int r = 0; r < 4; ++r) {
        int row = row0 + wr * 64 + i * 16 + quad * 4 + r;
        int col = col0 + wc * 64 + j * 16 + lr;
        O[(size_t)row * NN + col] = acc[i][j][r];
      }
}

// In-place combine: out[r][0:2048)=v, out[r][2048:4096)=u on entry.
// y[k]=v[k]+u[k]; y[4095-k]=u[k]-v[k]. Thread owns quad-pair {k0, kc=2044-k0}
// in both halves -> reads/writes closed under the thread, no hazard.
__global__ void combine_kernel(float* __restrict__ out) {
  int t = blockIdx.x * blockDim.x + threadIdx.x;   // 4096 rows * 256 pairs
  int r = t >> 8;
  int k0 = (t & 255) * 4;        // 0..1020
  int kc = 2044 - k0;            // 1024..2044 (disjoint from k0)
  float* row = out + (size_t)r * NN;
  float4 a = *(float4*)&row[k0];          // v[k0..k0+3]
  float4 b = *(float4*)&row[NH + k0];     // u[k0..k0+3]
  float4 c = *(float4*)&row[kc];          // v[kc..kc+3]
  float4 d = *(float4*)&row[NH + kc];     // u[kc..kc+3]
  float4 s0 = {a.x + b.x, a.y + b.y, a.z + b.z, a.w + b.w};
  float4 s1 = {c.x + d.x, c.y + d.y, c.z + d.z, c.w + d.w};
  float4 m0 = {b.w - a.w, b.z - a.z, b.y - a.y, b.x - a.x};   // y[2048+kc+j]
  float4 m1 = {d.w - c.w, d.z - c.z, d.y - c.y, d.x - c.x};   // y[2048+k0+j]
  *(float4*)&row[k0] = s0;
  *(float4*)&row[kc] = s1;
  *(float4*)&row[NH + kc] = m0;
  *(float4*)&row[NH + k0] = m1;
}

extern "C" void kernel_launch(void* const* d_in, const int* in_sizes, int n_in,
                              void* d_out, int out_size, void* d_ws, size_t ws_size,
                              hipStream_t stream) {
  const float* x = (const float*)d_in[0];
  float* out = (float*)d_out;
  unsigned short* xe = (unsigned short*)d_ws;            // 16 MB
  unsigned short* xo = xe + (size_t)NN * NH;             // 16 MB
  unsigned short* Be = xo + (size_t)NN * NH;             // 8 MB
  unsigned short* Bo = Be + (size_t)NH * NH;             // 8 MB

  prep_kernel<<<(NP8 + 2 * NB4) / 256, 256, 0, stream>>>(x, xe, xo, Be, Bo);

  dim3 grid(NH / TN, NN / TM, 2);
  gemm_vu_kernel<<<grid, 256, 0, stream>>>(xe, Be, out);

  combine_kernel<<<NN * 256 / 256, 256, 0, stream>>>(out);
}

// Round 5
// 209.325 us; speedup vs baseline: 1.4527x; 1.0127x over previous
//
#include <hip/hip_runtime.h>
#include <stdint.h>

// IDXST(4096x4096): y[r][k] = sum_n x[r][n] sin(pi*n*(2k+1)/8192).
// R5: two-level mirror fold. Level 1: y[k]=v[k]+u[k], y[4095-k]=u[k]-v[k]
// (k<2048), u = odd samples (DST-IV_2048), v = IDXST_2048(even samples).
// Level 2 on v: v[k']=p[k']+q[k'], v[2047-k']=q[k']-p[k'] (k'<1024),
// p = IDXST_1024(x[4t]), q = DST-IV_1024(x[4t+2]).
// Three GEMMs (U:4096x2048x2048, P,Q:4096x1024x1024) in ONE dispatch with the
// R4-proven block shape (single 4x4 acc, VGPR~92, 1024 blocks, XOR-swizzled
// LDS: 0 bank conflicts). U,P,Q staged into out[.,0:2048|2048:3072|3072:4096];
// one combine pass applies both fold levels (thread-closed quad sets).
// ws (44 MB): xo 16 | xee 8 | xeo 8 | Bo 8 | Bp 2 | Bq 2.

#define NN 4096
#define TM 128
#define TN 128
#define TK 64

typedef __attribute__((ext_vector_type(8))) short short8;
typedef __attribute__((ext_vector_type(4))) float f32x4;

__device__ __forceinline__ unsigned short f2bf(float f) {
  unsigned int u = __float_as_uint(f);
  u += 0x7fffu + ((u >> 16) & 1u);
  return (unsigned short)(u >> 16);
}

__device__ __forceinline__ void async_load16(const void* g, void* lds) {
  __builtin_amdgcn_global_load_lds(
      (const __attribute__((address_space(1))) unsigned int*)g,
      (__attribute__((address_space(3))) unsigned int*)lds, 16, 0, 0);
}

#define NXS (NN * NN / 8)        // 2M x-split threads (8 floats each)
#define NBO (2048 * 2048 / 4)    // 1M Bo threads
#define NBP (1024 * 1024 / 4)    // 256K Bp threads (Bq same)

// prep: xo[r][m]=x[r][2m+1]; xee[r][t]=x[r][4t]; xeo[r][t]=x[r][4t+2];
// Bo[c][m]=sin(pi(2m+1)(2c+1)/8192)  (c<2048, m<2048)
// Bp[c][t]=sin(pi*t*(2c+1)/2048)     (c<1024, t<1024)
// Bq[c][t]=sin(pi(2t+1)(2c+1)/4096)  (c<1024, t<1024)
__global__ void prep_kernel(const float* __restrict__ x,
                            unsigned short* __restrict__ xo,
                            unsigned short* __restrict__ xee,
                            unsigned short* __restrict__ xeo,
                            unsigned short* __restrict__ Bo,
                            unsigned short* __restrict__ Bp,
                            unsigned short* __restrict__ Bq) {
  int gi = blockIdx.x * blockDim.x + threadIdx.x;
  if (gi < NXS) {
    int g = gi & 511;            // 8-float group in row
    int r = gi >> 9;
    const float4* src = (const float4*)(x + (size_t)r * NN + g * 8);
    float4 v0 = src[0], v1 = src[1];    // n = 8g+0..3, 8g+4..7
    ushort4 ov;                          // odd n -> m = 4g..4g+3
    ov.x = f2bf(v0.y); ov.y = f2bf(v0.w); ov.z = f2bf(v1.y); ov.w = f2bf(v1.w);
    *(ushort4*)&xo[(size_t)r * 2048 + g * 4] = ov;
    unsigned int ee = ((unsigned)f2bf(v1.x) << 16) | f2bf(v0.x);  // t=2g,2g+1
    *(unsigned int*)&xee[(size_t)r * 1024 + g * 2] = ee;
    unsigned int eo = ((unsigned)f2bf(v1.z) << 16) | f2bf(v0.z);
    *(unsigned int*)&xeo[(size_t)r * 1024 + g * 2] = eo;
  } else if (gi < NXS + NBO) {
    int i = gi - NXS;
    int m0 = (i & 511) * 4;
    int c = i >> 9;
    unsigned int tw = 2u * (unsigned)c + 1u;
    const float sc = 3.14159265358979323846f / 8192.0f;
    ushort4 o; unsigned int ph;
    ph = ((unsigned)(2 * (m0 + 0) + 1) * tw) & 16383u; o.x = f2bf(__sinf((float)ph * sc));
    ph = ((unsigned)(2 * (m0 + 1) + 1) * tw) & 16383u; o.y = f2bf(__sinf((float)ph * sc));
    ph = ((unsigned)(2 * (m0 + 2) + 1) * tw) & 16383u; o.z = f2bf(__sinf((float)ph * sc));
    ph = ((unsigned)(2 * (m0 + 3) + 1) * tw) & 16383u; o.w = f2bf(__sinf((float)ph * sc));
    *(ushort4*)&Bo[(size_t)c * 2048 + m0] = o;
  } else if (gi < NXS + NBO + NBP) {
    int i = gi - NXS - NBO;
    int t0 = (i & 255) * 4;
    int c = i >> 8;
    unsigned int tw = 2u * (unsigned)c + 1u;
    const float sc = 3.14159265358979323846f / 2048.0f;
    ushort4 o; unsigned int ph;
    ph = ((unsigned)(t0 + 0) * tw) & 4095u; o.x = f2bf(__sinf((float)ph * sc));
    ph = ((unsigned)(t0 + 1) * tw) & 4095u; o.y = f2bf(__sinf((float)ph * sc));
    ph = ((unsigned)(t0 + 2) * tw) & 4095u; o.z = f2bf(__sinf((float)ph * sc));
    ph = ((unsigned)(t0 + 3) * tw) & 4095u; o.w = f2bf(__sinf((float)ph * sc));
    *(ushort4*)&Bp[(size_t)c * 1024 + t0] = o;
  } else {
    int i = gi - NXS - NBO - NBP;
    int t0 = (i & 255) * 4;
    int c = i >> 8;
    unsigned int tw = 2u * (unsigned)c + 1u;
    const float sc = 3.14159265358979323846f / 4096.0f;
    ushort4 o; unsigned int ph;
    ph = ((unsigned)(2 * (t0 + 0) + 1) * tw) & 8191u; o.x = f2bf(__sinf((float)ph * sc));
    ph = ((unsigned)(2 * (t0 + 1) + 1) * tw) & 8191u; o.y = f2bf(__sinf((float)ph * sc));
    ph = ((unsigned)(2 * (t0 + 2) + 1) * tw) & 8191u; o.z = f2bf(__sinf((float)ph * sc));
    ph = ((unsigned)(2 * (t0 + 3) + 1) * tw) & 8191u; o.w = f2bf(__sinf((float)ph * sc));
    *(ushort4*)&Bq[(size_t)c * 1024 + t0] = o;
  }
}

// Three GEMMs, one dispatch. bx<16: U(xo,Bo,K=2048)->cols[0,2048);
// bx<24: P(xee,Bp,K=1024)->cols[2048,3072); else Q(xeo,Bq,K=1024)->[3072,4096).
__global__ __launch_bounds__(256) void gemm3_kernel(
    const unsigned short* __restrict__ xo,
    const unsigned short* __restrict__ xee,
    const unsigned short* __restrict__ xeo,
    const unsigned short* __restrict__ Bo,
    const unsigned short* __restrict__ Bp,
    const unsigned short* __restrict__ Bq,
    float* __restrict__ out) {
  __shared__ __align__(16) unsigned short lA[TM * TK];
  __shared__ __align__(16) unsigned short lB[TN * TK];

  const int bx = blockIdx.x;
  const unsigned short* A;
  const unsigned short* Bm;
  int K, nloc0, col0;
  if (bx < 16)      { A = xo;  Bm = Bo; K = 2048; nloc0 = bx * 128;        col0 = nloc0; }
  else if (bx < 24) { A = xee; Bm = Bp; K = 1024; nloc0 = (bx - 16) * 128; col0 = 2048 + nloc0; }
  else              { A = xeo; Bm = Bq; K = 1024; nloc0 = (bx - 24) * 128; col0 = 3072 + nloc0; }

  const int tid = threadIdx.x;
  const int wave = tid >> 6;
  const int lane = tid & 63;
  const int quad = lane >> 4;
  const int lr = lane & 15;
  const int wr = wave >> 1;
  const int wc = wave & 1;

  const int row0 = blockIdx.y * TM;

  const int srow = wave * 8 + (lane >> 3);
  const int scol = ((lane & 7) ^ (lane >> 3)) * 8;   // XOR-swizzled chunk

  f32x4 acc[4][4];
#pragma unroll
  for (int i = 0; i < 4; ++i)
#pragma unroll
    for (int j = 0; j < 4; ++j)
      acc[i][j] = (f32x4){0.f, 0.f, 0.f, 0.f};

  for (int k0 = 0; k0 < K; k0 += TK) {
    __syncthreads();
#pragma unroll
    for (int r = 0; r < 4; ++r) {
      const int rr = r * 32 + srow;
      async_load16(&A[(size_t)(row0 + rr) * K + k0 + scol],
                   &lA[(r * 32 + wave * 8) * TK]);
      async_load16(&Bm[(size_t)(nloc0 + rr) * K + k0 + scol],
                   &lB[(r * 32 + wave * 8) * TK]);
    }
    __syncthreads();

#pragma unroll
    for (int kk = 0; kk < TK; kk += 32) {
      short8 af[4], bfv[4];
#pragma unroll
      for (int i = 0; i < 4; ++i) {
        const int sa = (((kk >> 3) + quad) ^ (lr & 7)) * 8;
        af[i]  = *(const short8*)&lA[(wr * 64 + i * 16 + lr) * TK + sa];
        bfv[i] = *(const short8*)&lB[(wc * 64 + i * 16 + lr) * TK + sa];
      }
#pragma unroll
      for (int i = 0; i < 4; ++i)
#pragma unroll
        for (int j = 0; j < 4; ++j)
          acc[i][j] = __builtin_amdgcn_mfma_f32_16x16x32_bf16(
              af[i], bfv[j], acc[i][j], 0, 0, 0);
    }
  }

  // C/D layout: col=lane&15, row=quad*4+reg
#pragma unroll
  for (int i = 0; i < 4; ++i)
#pragma unroll
    for (int j = 0; j < 4; ++j)
#pragma unroll
      for (int r = 0; r < 4; ++r) {
        int row = row0 + wr * 64 + i * 16 + quad * 4 + r;
        int cl = wc * 64 + j * 16 + lr;
        out[(size_t)row * NN + col0 + cl] = acc[i][j][r];
      }
}

// In-place combine, both fold levels. Row layout on entry:
// [0:2048)=u, [2048:3072)=p, [3072:4096)=q.
// v[k']=p+q, v[2047-k']=q-p (k'<1024); y[k]=v[k]+u[k], y[4095-k]=u[k]-v[k].
// Thread owns k'=k0..k0+3 AND mirrors 1020-k0..1023-k0: read set == write set.
__global__ void combine_kernel(float* __restrict__ out) {
  int t = blockIdx.x * blockDim.x + threadIdx.x;   // 4096 rows * 128 threads
  int r = t >> 7;
  int k0 = (t & 127) * 4;                          // [0,512)
  float* row = out + (size_t)r * NN;
  float U0[4], U1[4], U2[4], U3[4], P0[4], P1[4], Q0[4], Q1[4];
  *(float4*)U0 = *(float4*)&row[k0];          // u[k0+e]
  *(float4*)U1 = *(float4*)&row[1020 - k0];   // u[1020-k0+i] (u[1023-k'] rev)
  *(float4*)U2 = *(float4*)&row[1024 + k0];   // u[1024+k0+e]
  *(float4*)U3 = *(float4*)&row[2044 - k0];   // u[2047-k'] rev
  *(float4*)P0 = *(float4*)&row[2048 + k0];   // p[k0+e]
  *(float4*)P1 = *(float4*)&row[3068 - k0];   // p[1023-k'] rev
  *(float4*)Q0 = *(float4*)&row[3072 + k0];   // q[k0+e]
  *(float4*)Q1 = *(float4*)&row[4092 - k0];   // q[1023-k'] rev
  float YA[4], YB[4], YC[4], YD[4], YE[4], YF[4], YG[4], YH[4];
#pragma unroll
  for (int e = 0; e < 4; ++e) {
    // primary k' = k0+e
    float v1 = P0[e] + Q0[e];        // v[k']
    float v2 = Q0[e] - P0[e];        // v[2047-k']
    float um = U3[3 - e];            // u[2047-k']
    YA[e] = v1 + U0[e];              // y[k']          @ k0 fwd
    YB[3 - e] = U0[e] - v1;          // y[4095-k']     @ 4092-k0 rev
    YC[3 - e] = v2 + um;             // y[2047-k']     @ 2044-k0 rev
    YD[e] = um - v2;                 // y[2048+k']     @ 2048+k0 fwd
    // mirror k'' = 1023-k'
    float pm = P1[3 - e], qm = Q1[3 - e];
    float w1 = pm + qm;              // v[k'']
    float w2 = qm - pm;              // v[2047-k''] = v[1024+k']
    float umm = U1[3 - e];           // u[k''] = u[1023-k']
    YE[3 - e] = w1 + umm;            // y[1023-k']     @ 1020-k0 rev
    YF[e] = umm - w1;                // y[3072+k']     @ 3072+k0 fwd
    YG[e] = w2 + U2[e];              // y[1024+k']     @ 1024+k0 fwd
    YH[3 - e] = U2[e] - w2;          // y[3071-k']     @ 3068-k0 rev
  }
  *(float4*)&row[k0] = *(float4*)YA;
  *(float4*)&row[4092 - k0] = *(float4*)YB;
  *(float4*)&row[2044 - k0] = *(float4*)YC;
  *(float4*)&row[2048 + k0] = *(float4*)YD;
  *(float4*)&row[1020 - k0] = *(float4*)YE;
  *(float4*)&row[3072 + k0] = *(float4*)YF;
  *(float4*)&row[1024 + k0] = *(float4*)YG;
  *(float4*)&row[3068 - k0] = *(float4*)YH;
}

extern "C" void kernel_launch(void* const* d_in, const int* in_sizes, int n_in,
                              void* d_out, int out_size, void* d_ws, size_t ws_size,
                              hipStream_t stream) {
  const float* x = (const float*)d_in[0];
  float* out = (float*)d_out;
  unsigned short* xo  = (unsigned short*)d_ws;            // 16 MB
  unsigned short* xee = xo + (size_t)NN * 2048;           // 8 MB
  unsigned short* xeo = xee + (size_t)NN * 1024;          // 8 MB
  unsigned short* Bo  = xeo + (size_t)NN * 1024;          // 8 MB
  unsigned short* Bp  = Bo + (size_t)2048 * 2048;         // 2 MB
  unsigned short* Bq  = Bp + (size_t)1024 * 1024;         // 2 MB -> 44 MB total

  int prep_threads = NXS + NBO + 2 * NBP;
  prep_kernel<<<prep_threads / 256, 256, 0, stream>>>(x, xo, xee, xeo, Bo, Bp, Bq);

  dim3 grid(32, NN / TM);
  gemm3_kernel<<<grid, 256, 0, stream>>>(xo, xee, xeo, Bo, Bp, Bq, out);

  combine_kernel<<<NN * 128 / 256, 256, 0, stream>>>(out);
}